// Round 17
// baseline (200.693 us; speedup 1.0000x reference)
//
#include <hip/hip_runtime.h>
#include <math.h>

typedef _Float16 half8 __attribute__((ext_vector_type(8)));
typedef __fp16   fp16x2 __attribute__((ext_vector_type(2)));  // cvt_pkrtz's return type
typedef float f32x4 __attribute__((ext_vector_type(4)));

// Branchless exact-grade GELU: x*0.5*(1+erf(x/sqrt(2))) with A&S 7.1.26 erf,
// |erf err| <= 1.5e-7 (vs output threshold 2.47e-2).
__device__ __forceinline__ float gelu_f(float v) {
    float y  = v * 0.70710678118654752f;
    float ay = __builtin_fabsf(y);
    float t  = __builtin_amdgcn_rcpf(__builtin_fmaf(0.3275911f, ay, 1.0f));
    float p  = __builtin_fmaf(t, 1.061405429f, -1.453152027f);
    p = __builtin_fmaf(p, t, 1.421413741f);
    p = __builtin_fmaf(p, t, -0.284496736f);
    p = __builtin_fmaf(p, t, 0.254829592f);
    p = p * t;
    float e  = __builtin_amdgcn_exp2f(ay * ay * -1.4426950408889634f);
    float er = __builtin_fmaf(-p, e, 1.0f);        // erf(|y|), saturates to 1
    er = __builtin_copysignf(er, v);               // restore sign
    float hv = 0.5f * v;
    return __builtin_fmaf(hv, er, hv);
}

// Sum over the 16 lanes of a DPP row (our c index) via row_ror rotate-reduce.
__device__ __forceinline__ float rowsum16(float v) {
    int t;
    t = __builtin_amdgcn_update_dpp(0, __float_as_int(v), 0x121, 0xf, 0xf, true); // ror:1
    v += __int_as_float(t);
    t = __builtin_amdgcn_update_dpp(0, __float_as_int(v), 0x122, 0xf, 0xf, true); // ror:2
    v += __int_as_float(t);
    t = __builtin_amdgcn_update_dpp(0, __float_as_int(v), 0x124, 0xf, 0xf, true); // ror:4
    v += __int_as_float(t);
    t = __builtin_amdgcn_update_dpp(0, __float_as_int(v), 0x128, 0xf, 0xf, true); // ror:8
    v += __int_as_float(t);
    return v;
}

#define MFMA16(A, B, C) __builtin_amdgcn_mfma_f32_16x16x32_f16((A), (B), (C), 0, 0, 0)

union H8u { half8 h8; fp16x2 h2[4]; };

// One wave owns a 16-row tile end-to-end.  fp16 MFMA, fp32 accum.
// A-frag: row = lane&15, k = 32*s + 8*(lane>>4) + j.  C-layout (m89):
// col = lane&15, row = 4*(lane>>4) + reg.
//
// r10..r16 all land at 97+-2us with no saturated pipe -> suspicion: the
// "6 waves/SIMD" experiments never actually ran at 6 (VGPR side of
// residency unverified; if compiler picked >85 regs, LDS-3-block configs
// collapsed to 2 blocks = 4 waves/SIMD = r10).  This round FORCES the
// 6-wave data point: __launch_bounds__(512,6) pins VGPR<=85 (above the
// observed natural ~64, so not a forced-gap spill) and the activation
// buffers (xstage/h1/h2) OVERLAY one per-wave 3584B region so LDS/block =
// 18432 + 8*3584 = 47104 -> 3 blocks/CU * 8 waves = 24 waves/CU.
// Overlay safety: per-wave DS ops execute in order (x-frag reads precede
// h1 writes; h2 disjoint from h1; next tile's staging follows this tile's
// last h2 read in program order).  Pointers NOT __restrict__ (they alias).
// k-pad (cols 73..95) holds stale-but-finite fp16 garbage after tile 0
// (zeroed once); W1's k>=73 fragment entries are zero, so garbage*0 = 0.
__global__ __launch_bounds__(512, 6) void mlp_mfma_kernel(
    const float* __restrict__ x,
    const float* __restrict__ alpha,
    const float* __restrict__ beta,
    const float* __restrict__ gamma,
    const float* __restrict__ gscal,
    const float* __restrict__ W1, const float* __restrict__ b1,
    const float* __restrict__ W2, const float* __restrict__ b2,
    const float* __restrict__ Wres, const float* __restrict__ bres,
    const float* __restrict__ W6, const float* __restrict__ b6,
    float* __restrict__ out, int B)
{
    const int lane = threadIdx.x & 63;
    const int wid  = threadIdx.x >> 6;   // 0..7
    const int c    = lane & 15;   // col (N) index / A-row index
    const int g    = lane >> 4;   // k-group 0..3

    // Weight-fragment table (block-shared): frags 0..11 = W1[t*3+s],
    // 12..15 = W2, 16..17 = Wres.  18 frags x 64 lanes x 16B.
    __shared__ __align__(16) _Float16 wtab[18 * 512];
    // Per-wave overlaid activation region (1792 halves = 3584B):
    //   xstage: rows 0..15, pitch 96  -> [0..1535]
    //   h1:     rows 0..15, pitch 72  -> [0..1151]
    //   h2:     rows 0..15, pitch 40  -> [1152..1791]
    __shared__ __align__(16) _Float16 acts[8][1792];
    _Float16* actb = acts[wid];          // NOT restrict: regions alias

    // ---- build weight tables once (wave 0) ----
    if (wid == 0) {
        float gm[8];
        #pragma unroll
        for (int j = 0; j < 8; ++j) {
            int k  = 8 * g + j;
            int kc = k < 3 ? 3 : (k > 22 ? 22 : k);     // clamp: safe load
            float gv = gamma[kc];
            gm[j] = (k >= 3 && k < 23) ? gv : 1.0f;
        }
        #pragma unroll
        for (int t = 0; t < 4; ++t)
            #pragma unroll
            for (int s = 0; s < 3; ++s)
                #pragma unroll
                for (int j = 0; j < 8; ++j) {
                    int k  = 32 * s + 8 * g + j;
                    int kc = k < 73 ? k : 72;           // clamp: no OOB load
                    float v = W1[(16 * t + c) * 73 + kc];
                    if (s == 0) v *= gm[j];             // gamma folded into s=0
                    wtab[(t * 3 + s) * 512 + lane * 8 + j] =
                        (k < 73) ? (_Float16)v : (_Float16)0.f;   // zero k-pad kills xs garbage
                }
        #pragma unroll
        for (int t = 0; t < 2; ++t)
            #pragma unroll
            for (int s = 0; s < 2; ++s)
                #pragma unroll
                for (int j = 0; j < 8; ++j)
                    wtab[(12 + t * 2 + s) * 512 + lane * 8 + j] =
                        (_Float16)W2[(16 * t + c) * 64 + 32 * s + 8 * g + j];
        #pragma unroll
        for (int t = 0; t < 2; ++t)
            #pragma unroll
            for (int j = 0; j < 8; ++j)
                wtab[(16 + t) * 512 + lane * 8 + j] =
                    (_Float16)Wres[(16 * t + c) * 32 + 8 * g + j];
    }

    // zero this wave's activation region once (tile-0 garbage must be finite)
    for (int i = lane; i < 1792; i += 64) actb[i] = (_Float16)0.f;

    // biases / final weights in registers (10 regs)
    float b1f[4], b2f[2], brf[2], w6f[2];
    #pragma unroll
    for (int t = 0; t < 4; ++t) b1f[t] = b1[16 * t + c];
    #pragma unroll
    for (int t = 0; t < 2; ++t) { b2f[t] = b2[16 * t + c]; brf[t] = bres[16 * t + c]; w6f[t] = W6[16 * t + c]; }
    const float b6g = b6[0] + gscal[0];

    __syncthreads();   // wtab visible to all waves

    const _Float16* wt = wtab + lane * 8;   // shared vaddr; frag f at +f*512

    // W2 / Wres frags hoisted to registers (block-invariant; -6 LDS reads/tile)
    half8 w2f[2][2], wrf[2];
    #pragma unroll
    for (int t = 0; t < 2; ++t)
        #pragma unroll
        for (int s = 0; s < 2; ++s)
            w2f[t][s] = *reinterpret_cast<const half8*>(wt + (12 + t * 2 + s) * 512);
    #pragma unroll
    for (int t = 0; t < 2; ++t)
        wrf[t] = *reinterpret_cast<const half8*>(wt + (16 + t) * 512);

    const int ntiles = B >> 4;
    const int totw   = gridDim.x * 8;
    for (int tile = blockIdx.x * 8 + wid; tile < ntiles; tile += totw) {
        const int R0 = tile << 4;
        const float* __restrict__ xt = x + (size_t)R0 * 73;

        // ---- embed chain first (f32-exact indices; g==0 lanes only) ----
        float x0 = 0.f, x1 = 0.f, xa = 0.f, xb = 0.f;
        if (g == 0) {
            x0 = xt[c * 73];
            x1 = xt[c * 73 + 1];
        }

        // ---- coalesced tile load: 19 x global_load_dword, lane i <- elem 64j+i ----
        float lf[19];
        #pragma unroll
        for (int j = 0; j < 18; ++j) lf[j] = xt[64 * j + lane];
        lf[18] = (lane < 16) ? xt[64 * 18 + lane] : 0.f;

        if (g == 0) {
            xa = alpha[(int)x0];
            xb = beta[(int)x1];
        }

        // ---- stage to LDS fp16 (pitch 96; consecutive lanes -> consecutive
        //      halves: conflict-free).  In-order DS: these writes land before
        //      the frag reads below read them (same wave). ----
        {
            int row = 0, col = lane;   // element e = 64j + lane
            #pragma unroll
            for (int j = 0; j < 19; ++j) {
                if (j < 18 || lane < 16)
                    actb[row * 96 + col] = (_Float16)lf[j];
                col += 64;
                int wrap = (col >= 73) ? 1 : 0;
                col -= wrap ? 73 : 0;
                row += wrap;
            }
        }

        asm volatile("s_waitcnt lgkmcnt(0)" ::: "memory");

        // ---- A-frags from staged fp16 (aligned b128; k-pad handled by
        //      zeroed W1 fragment entries) ----
        const _Float16* xrow = actb + c * 96;
        half8 a1f = *reinterpret_cast<const half8*>(xrow + 32 + 8 * g);
        half8 a2f = *reinterpret_cast<const half8*>(xrow + 64 + 8 * g);
        H8u a0u;
        a0u.h8 = *reinterpret_cast<const half8*>(xrow + 8 * g);
        {
            fp16x2 we = __builtin_amdgcn_cvt_pkrtz(xa, xb);
            if (g == 0) a0u.h2[0] = we;   // embed cols 0/1 on g==0 lanes
        }

        // ---- layer 1: 73->64 (W1 frags from LDS; k0 last to cover gathers) ----
        f32x4 acc[4];
        #pragma unroll
        for (int t = 0; t < 4; ++t) { f32x4 z = { b1f[t], b1f[t], b1f[t], b1f[t] }; acc[t] = z; }
        #pragma unroll
        for (int t = 0; t < 4; ++t)
            acc[t] = MFMA16(a1f, *reinterpret_cast<const half8*>(wt + (t * 3 + 1) * 512), acc[t]);
        #pragma unroll
        for (int t = 0; t < 4; ++t)
            acc[t] = MFMA16(a2f, *reinterpret_cast<const half8*>(wt + (t * 3 + 2) * 512), acc[t]);
        #pragma unroll
        for (int t = 0; t < 4; ++t)
            acc[t] = MFMA16(a0u.h8, *reinterpret_cast<const half8*>(wt + (t * 3 + 0) * 512), acc[t]);

        // GELU -> h1 (overlays xstage; x-frag reads above already completed)
        #pragma unroll
        for (int t = 0; t < 4; ++t)
            #pragma unroll
            for (int r = 0; r < 4; ++r)
                actb[(4 * g + r) * 72 + 16 * t + c] = (_Float16)gelu_f(acc[t][r]);

        asm volatile("s_waitcnt lgkmcnt(0)" ::: "memory");

        // ---- layer 2: 64->32 (weights in regs) ----
        half8 a2f0 = *reinterpret_cast<const half8*>(actb + c * 72 + 8 * g);
        half8 a2f1 = *reinterpret_cast<const half8*>(actb + c * 72 + 32 + 8 * g);
        f32x4 ac2[2];
        #pragma unroll
        for (int t = 0; t < 2; ++t) {
            f32x4 z = { b2f[t], b2f[t], b2f[t], b2f[t] };
            z = MFMA16(a2f0, w2f[t][0], z);
            ac2[t] = MFMA16(a2f1, w2f[t][1], z);
        }
        float h2c[2][4];
        #pragma unroll
        for (int t = 0; t < 2; ++t)
            #pragma unroll
            for (int r = 0; r < 4; ++r)
                h2c[t][r] = gelu_f(ac2[t][r]);

        // h2 to [1152..1791] (disjoint from h1; pitch 40)
        #pragma unroll
        for (int t = 0; t < 2; ++t)
            #pragma unroll
            for (int r = 0; r < 4; ++r)
                actb[1152 + (4 * g + r) * 40 + 16 * t + c] = (_Float16)h2c[t][r];

        asm volatile("s_waitcnt lgkmcnt(0)" ::: "memory");

        // ---- residual layer: C-init = bres + h2 (weights in regs) ----
        half8 arf = *reinterpret_cast<const half8*>(actb + 1152 + c * 40 + 8 * g);
        f32x4 acr[2];
        #pragma unroll
        for (int t = 0; t < 2; ++t) {
            f32x4 z = { brf[t] + h2c[t][0], brf[t] + h2c[t][1],
                        brf[t] + h2c[t][2], brf[t] + h2c[t][3] };
            acr[t] = MFMA16(arf, wrf[t], z);
        }

        // ---- final 32->1: per-lane partial, DPP rotate-reduce over c ----
        f32x4 p;
        #pragma unroll
        for (int r = 0; r < 4; ++r)
            p[r] = rowsum16(gelu_f(acr[0][r]) * w6f[0] + gelu_f(acr[1][r]) * w6f[1]);
        if (c == 0) {
            f32x4 o = { p[0] + b6g, p[1] + b6g, p[2] + b6g, p[3] + b6g };
            *reinterpret_cast<f32x4*>(out + R0 + 4 * g) = o;  // rows R0+4g..+3
        }
    }
}

extern "C" void kernel_launch(void* const* d_in, const int* in_sizes, int n_in,
                              void* d_out, int out_size, void* d_ws, size_t ws_size,
                              hipStream_t stream) {
    const float* x     = (const float*)d_in[0];
    const float* alpha = (const float*)d_in[1];
    const float* beta  = (const float*)d_in[2];
    const float* gamma = (const float*)d_in[3];
    const float* g     = (const float*)d_in[4];
    const float* W1    = (const float*)d_in[5];
    const float* b1    = (const float*)d_in[6];
    const float* W2    = (const float*)d_in[7];
    const float* b2    = (const float*)d_in[8];
    const float* Wres  = (const float*)d_in[9];
    const float* bres  = (const float*)d_in[10];
    const float* W6    = (const float*)d_in[11];
    const float* b6    = (const float*)d_in[12];
    float* out = (float*)d_out;

    int B = out_size;          // 1e6 rows; divisible by 16
    // 768 blocks x 512 threads = 3 blocks/CU (LDS 47104 x 3 = 141KB) x
    // 8 waves = 24 waves/CU = 6 waves/SIMD, guaranteed by the VGPR<=85 pin.
    int nblocks = 768;
    mlp_mfma_kernel<<<nblocks, 512, 0, stream>>>(x, alpha, beta, gamma, g,
                                                 W1, b1, W2, b2, Wres, bres,
                                                 W6, b6, out, B);
}

// Round 18
// 195.213 us; speedup vs baseline: 1.0281x; 1.0281x over previous
//
#include <hip/hip_runtime.h>
#include <math.h>

typedef _Float16 half8 __attribute__((ext_vector_type(8)));
typedef __fp16   fp16x2 __attribute__((ext_vector_type(2)));  // cvt_pkrtz's return type
typedef float f32x4 __attribute__((ext_vector_type(4)));

// Branchless exact-grade GELU: x*0.5*(1+erf(x/sqrt(2))) with A&S 7.1.26 erf,
// |erf err| <= 1.5e-7 (vs output threshold 2.47e-2).
__device__ __forceinline__ float gelu_f(float v) {
    float y  = v * 0.70710678118654752f;
    float ay = __builtin_fabsf(y);
    float t  = __builtin_amdgcn_rcpf(__builtin_fmaf(0.3275911f, ay, 1.0f));
    float p  = __builtin_fmaf(t, 1.061405429f, -1.453152027f);
    p = __builtin_fmaf(p, t, 1.421413741f);
    p = __builtin_fmaf(p, t, -0.284496736f);
    p = __builtin_fmaf(p, t, 0.254829592f);
    p = p * t;
    float e  = __builtin_amdgcn_exp2f(ay * ay * -1.4426950408889634f);
    float er = __builtin_fmaf(-p, e, 1.0f);        // erf(|y|), saturates to 1
    er = __builtin_copysignf(er, v);               // restore sign
    float hv = 0.5f * v;
    return __builtin_fmaf(hv, er, hv);
}

// Sum over the 16 lanes of a DPP row (our c index) via row_ror rotate-reduce.
__device__ __forceinline__ float rowsum16(float v) {
    int t;
    t = __builtin_amdgcn_update_dpp(0, __float_as_int(v), 0x121, 0xf, 0xf, true); // ror:1
    v += __int_as_float(t);
    t = __builtin_amdgcn_update_dpp(0, __float_as_int(v), 0x122, 0xf, 0xf, true); // ror:2
    v += __int_as_float(t);
    t = __builtin_amdgcn_update_dpp(0, __float_as_int(v), 0x124, 0xf, 0xf, true); // ror:4
    v += __int_as_float(t);
    t = __builtin_amdgcn_update_dpp(0, __float_as_int(v), 0x128, 0xf, 0xf, true); // ror:8
    v += __int_as_float(t);
    return v;
}

#define MFMA16(A, B, C) __builtin_amdgcn_mfma_f32_16x16x32_f16((A), (B), (C), 0, 0, 0)

union H8u { half8 h8; fp16x2 h2[4]; };

// One wave owns a 16-row tile end-to-end.  fp16 MFMA, fp32 accum.
// A-frag: row = lane&15, k = 32*s + 8*(lane>>4) + j.  C-layout (m89):
// col = lane&15, row = 4*(lane>>4) + reg.
//
// r10/r14/r16 all sit at 97+-2us across 4 and 6 waves/SIMD, scattered and
// coalesced loads, with no pipe saturated.  The one shared constant: THREE
// asm volatile("s_waitcnt lgkmcnt(0)":::"memory") drains per tile.  The
// compiler inserts counted lgkmcnt waits for same-wave LDS RAW on its own
// (m97 asm evidence); a full drain waits on ALL ~31 outstanding DS ops when
// the next read needs only the last few, and the "memory" clobber is a
// scheduling fence that has blocked cross-phase/cross-iteration overlap in
// every round (the m141 lesson, self-inflicted).  This round: r16 with the
// drains DELETED.  Single variable.  The scheduler may also LICM-hoist the
// 12 loop-invariant W1 frags (+48 regs, est ~112-125 < the (512,4)=128 cap).
__global__ __launch_bounds__(512, 4) void mlp_mfma_kernel(
    const float* __restrict__ x,
    const float* __restrict__ alpha,
    const float* __restrict__ beta,
    const float* __restrict__ gamma,
    const float* __restrict__ gscal,
    const float* __restrict__ W1, const float* __restrict__ b1,
    const float* __restrict__ W2, const float* __restrict__ b2,
    const float* __restrict__ Wres, const float* __restrict__ bres,
    const float* __restrict__ W6, const float* __restrict__ b6,
    float* __restrict__ out, int B)
{
    const int lane = threadIdx.x & 63;
    const int wid  = threadIdx.x >> 6;   // 0..7
    const int c    = lane & 15;   // col (N) index / A-row index
    const int g    = lane >> 4;   // k-group 0..3

    // Weight-fragment table (block-shared): frags 0..11 = W1[t*3+s],
    // 12..15 = W2, 16..17 = Wres.  18 frags x 64 lanes x 16B.
    __shared__ __align__(16) _Float16 wtab[18 * 512];
    // per-wave coalesced x staging: 16 rows x 96 halves (pitch 192B)
    __shared__ __align__(16) _Float16 xstage[8][16 * 96];
    // per-wave activation staging
    __shared__ __align__(16) _Float16 h1buf[8][16 * 72];
    __shared__ __align__(16) _Float16 h2buf[8][16 * 40];
    _Float16* __restrict__ xs  = xstage[wid];
    _Float16* __restrict__ h1b = h1buf[wid];
    _Float16* __restrict__ h2b = h2buf[wid];

    // ---- build weight tables once (wave 0) ----
    if (wid == 0) {
        float gm[8];
        #pragma unroll
        for (int j = 0; j < 8; ++j) {
            int k  = 8 * g + j;
            int kc = k < 3 ? 3 : (k > 22 ? 22 : k);     // clamp: safe load
            float gv = gamma[kc];
            gm[j] = (k >= 3 && k < 23) ? gv : 1.0f;
        }
        #pragma unroll
        for (int t = 0; t < 4; ++t)
            #pragma unroll
            for (int s = 0; s < 3; ++s)
                #pragma unroll
                for (int j = 0; j < 8; ++j) {
                    int k  = 32 * s + 8 * g + j;
                    int kc = k < 73 ? k : 72;           // clamp: no OOB load
                    float v = W1[(16 * t + c) * 73 + kc];
                    if (s == 0) v *= gm[j];             // gamma folded into s=0
                    wtab[(t * 3 + s) * 512 + lane * 8 + j] =
                        (k < 73) ? (_Float16)v : (_Float16)0.f;   // zero k-pad
                }
        #pragma unroll
        for (int t = 0; t < 2; ++t)
            #pragma unroll
            for (int s = 0; s < 2; ++s)
                #pragma unroll
                for (int j = 0; j < 8; ++j)
                    wtab[(12 + t * 2 + s) * 512 + lane * 8 + j] =
                        (_Float16)W2[(16 * t + c) * 64 + 32 * s + 8 * g + j];
        #pragma unroll
        for (int t = 0; t < 2; ++t)
            #pragma unroll
            for (int j = 0; j < 8; ++j)
                wtab[(16 + t) * 512 + lane * 8 + j] =
                    (_Float16)Wres[(16 * t + c) * 32 + 8 * g + j];
    }

    // zero the k-pad (cols 73..95) of this wave's xstage, once
    for (int idx = lane; idx < 16 * 23; idx += 64) {
        int r_ = idx / 23;
        int c_ = 73 + (idx - r_ * 23);
        xs[r_ * 96 + c_] = (_Float16)0.f;
    }

    // biases / final weights in registers (10 regs)
    float b1f[4], b2f[2], brf[2], w6f[2];
    #pragma unroll
    for (int t = 0; t < 4; ++t) b1f[t] = b1[16 * t + c];
    #pragma unroll
    for (int t = 0; t < 2; ++t) { b2f[t] = b2[16 * t + c]; brf[t] = bres[16 * t + c]; w6f[t] = W6[16 * t + c]; }
    const float b6g = b6[0] + gscal[0];

    __syncthreads();   // wtab visible to all waves

    const _Float16* wt = wtab + lane * 8;   // shared vaddr; frag f at +f*512

    // W2 / Wres frags in registers (block-invariant)
    half8 w2f[2][2], wrf[2];
    #pragma unroll
    for (int t = 0; t < 2; ++t)
        #pragma unroll
        for (int s = 0; s < 2; ++s)
            w2f[t][s] = *reinterpret_cast<const half8*>(wt + (12 + t * 2 + s) * 512);
    #pragma unroll
    for (int t = 0; t < 2; ++t)
        wrf[t] = *reinterpret_cast<const half8*>(wt + (16 + t) * 512);

    const int ntiles = B >> 4;
    const int totw   = gridDim.x * 8;
    for (int tile = blockIdx.x * 8 + wid; tile < ntiles; tile += totw) {
        const int R0 = tile << 4;
        const float* __restrict__ xt = x + (size_t)R0 * 73;

        // ---- embed chain first (f32-exact indices; g==0 lanes only) ----
        float x0 = 0.f, x1 = 0.f, xa = 0.f, xb = 0.f;
        if (g == 0) {
            x0 = xt[c * 73];
            x1 = xt[c * 73 + 1];
        }

        // ---- coalesced tile load: 19 x global_load_dword, lane i <- elem 64j+i ----
        float lf[19];
        #pragma unroll
        for (int j = 0; j < 18; ++j) lf[j] = xt[64 * j + lane];
        lf[18] = (lane < 16) ? xt[64 * 18 + lane] : 0.f;

        if (g == 0) {
            xa = alpha[(int)x0];
            xb = beta[(int)x1];
        }

        // ---- stage to LDS fp16 (pitch 96; consecutive lanes -> consecutive
        //      halves: conflict-free).  Compiler inserts the counted lgkmcnt
        //      waits between these writes and the frag reads below. ----
        {
            int row = 0, col = lane;   // element e = 64j + lane
            #pragma unroll
            for (int j = 0; j < 19; ++j) {
                if (j < 18 || lane < 16)
                    xs[row * 96 + col] = (_Float16)lf[j];
                col += 64;
                int wrap = (col >= 73) ? 1 : 0;
                col -= wrap ? 73 : 0;
                row += wrap;
            }
        }

        // ---- A-frags from staged fp16 (aligned b128 reads) ----
        const _Float16* xrow = xs + c * 96;
        half8 a1f = *reinterpret_cast<const half8*>(xrow + 32 + 8 * g);
        half8 a2f = *reinterpret_cast<const half8*>(xrow + 64 + 8 * g);
        H8u a0u;
        a0u.h8 = *reinterpret_cast<const half8*>(xrow + 8 * g);
        {
            fp16x2 we = __builtin_amdgcn_cvt_pkrtz(xa, xb);
            if (g == 0) a0u.h2[0] = we;   // embed cols 0/1 on g==0 lanes
        }

        // ---- layer 1: 73->64 (W1 frags from LDS; k0 last to cover gathers) ----
        f32x4 acc[4];
        #pragma unroll
        for (int t = 0; t < 4; ++t) { f32x4 z = { b1f[t], b1f[t], b1f[t], b1f[t] }; acc[t] = z; }
        #pragma unroll
        for (int t = 0; t < 4; ++t)
            acc[t] = MFMA16(a1f, *reinterpret_cast<const half8*>(wt + (t * 3 + 1) * 512), acc[t]);
        #pragma unroll
        for (int t = 0; t < 4; ++t)
            acc[t] = MFMA16(a2f, *reinterpret_cast<const half8*>(wt + (t * 3 + 2) * 512), acc[t]);
        #pragma unroll
        for (int t = 0; t < 4; ++t)
            acc[t] = MFMA16(a0u.h8, *reinterpret_cast<const half8*>(wt + (t * 3 + 0) * 512), acc[t]);

        // GELU -> h1 to LDS (row = 4g+r, col = 16t+c, stride 72)
        #pragma unroll
        for (int t = 0; t < 4; ++t)
            #pragma unroll
            for (int r = 0; r < 4; ++r)
                h1b[(4 * g + r) * 72 + 16 * t + c] = (_Float16)gelu_f(acc[t][r]);

        // ---- layer 2: 64->32 (weights in regs; compiler orders h1 RAW) ----
        half8 a2f0 = *reinterpret_cast<const half8*>(&h1b[c * 72 + 8 * g]);
        half8 a2f1 = *reinterpret_cast<const half8*>(&h1b[c * 72 + 32 + 8 * g]);
        f32x4 ac2[2];
        #pragma unroll
        for (int t = 0; t < 2; ++t) {
            f32x4 z = { b2f[t], b2f[t], b2f[t], b2f[t] };
            z = MFMA16(a2f0, w2f[t][0], z);
            ac2[t] = MFMA16(a2f1, w2f[t][1], z);
        }
        float h2c[2][4];
        #pragma unroll
        for (int t = 0; t < 2; ++t)
            #pragma unroll
            for (int r = 0; r < 4; ++r)
                h2c[t][r] = gelu_f(ac2[t][r]);

        // h2 to LDS (stride 40)
        #pragma unroll
        for (int t = 0; t < 2; ++t)
            #pragma unroll
            for (int r = 0; r < 4; ++r)
                h2b[(4 * g + r) * 40 + 16 * t + c] = (_Float16)h2c[t][r];

        // ---- residual layer: C-init = bres + h2 (weights in regs) ----
        half8 arf = *reinterpret_cast<const half8*>(&h2b[c * 40 + 8 * g]);
        f32x4 acr[2];
        #pragma unroll
        for (int t = 0; t < 2; ++t) {
            f32x4 z = { brf[t] + h2c[t][0], brf[t] + h2c[t][1],
                        brf[t] + h2c[t][2], brf[t] + h2c[t][3] };
            acr[t] = MFMA16(arf, wrf[t], z);
        }

        // ---- final 32->1: per-lane partial, DPP rotate-reduce over c ----
        f32x4 p;
        #pragma unroll
        for (int r = 0; r < 4; ++r)
            p[r] = rowsum16(gelu_f(acr[0][r]) * w6f[0] + gelu_f(acr[1][r]) * w6f[1]);
        if (c == 0) {
            f32x4 o = { p[0] + b6g, p[1] + b6g, p[2] + b6g, p[3] + b6g };
            *reinterpret_cast<f32x4*>(out + R0 + 4 * g) = o;  // rows R0+4g..+3
        }
    }
}

extern "C" void kernel_launch(void* const* d_in, const int* in_sizes, int n_in,
                              void* d_out, int out_size, void* d_ws, size_t ws_size,
                              hipStream_t stream) {
    const float* x     = (const float*)d_in[0];
    const float* alpha = (const float*)d_in[1];
    const float* beta  = (const float*)d_in[2];
    const float* gamma = (const float*)d_in[3];
    const float* g     = (const float*)d_in[4];
    const float* W1    = (const float*)d_in[5];
    const float* b1    = (const float*)d_in[6];
    const float* W2    = (const float*)d_in[7];
    const float* b2    = (const float*)d_in[8];
    const float* Wres  = (const float*)d_in[9];
    const float* bres  = (const float*)d_in[10];
    const float* W6    = (const float*)d_in[11];
    const float* b6    = (const float*)d_in[12];
    float* out = (float*)d_out;

    int B = out_size;          // 1e6 rows; divisible by 16
    // 512 blocks x 512 threads: LDS 71680 B/block -> 2 blocks/CU, 16 waves/CU.
    int nblocks = 512;
    mlp_mfma_kernel<<<nblocks, 512, 0, stream>>>(x, alpha, beta, gamma, g,
                                                 W1, b1, W2, b2, Wres, bres,
                                                 W6, b6, out, B);
}

// Round 19
// 100.490 us; speedup vs baseline: 1.9972x; 1.9426x over previous
//
#include <hip/hip_runtime.h>
#include <math.h>

typedef _Float16 half8 __attribute__((ext_vector_type(8)));
typedef __fp16   fp16x2 __attribute__((ext_vector_type(2)));  // cvt_pkrtz's return type
typedef float f32x4 __attribute__((ext_vector_type(4)));

// Branchless exact-grade GELU: x*0.5*(1+erf(x/sqrt(2))) with A&S 7.1.26 erf,
// |erf err| <= 1.5e-7 (vs output threshold 2.47e-2).
__device__ __forceinline__ float gelu_f(float v) {
    float y  = v * 0.70710678118654752f;
    float ay = __builtin_fabsf(y);
    float t  = __builtin_amdgcn_rcpf(__builtin_fmaf(0.3275911f, ay, 1.0f));
    float p  = __builtin_fmaf(t, 1.061405429f, -1.453152027f);
    p = __builtin_fmaf(p, t, 1.421413741f);
    p = __builtin_fmaf(p, t, -0.284496736f);
    p = __builtin_fmaf(p, t, 0.254829592f);
    p = p * t;
    float e  = __builtin_amdgcn_exp2f(ay * ay * -1.4426950408889634f);
    float er = __builtin_fmaf(-p, e, 1.0f);        // erf(|y|), saturates to 1
    er = __builtin_copysignf(er, v);               // restore sign
    float hv = 0.5f * v;
    return __builtin_fmaf(hv, er, hv);
}

#define MFMA16(A, B, C) __builtin_amdgcn_mfma_f32_16x16x32_f16((A), (B), (C), 0, 0, 0)

// One wave owns a 16-row tile end-to-end.  fp16 MFMA, fp32 accum.
// A-frag: row = lane&15, k = 32*s + 8*(lane>>4) + j.  C-layout (m89):
// col = lane&15, row = 4*(lane>>4) + reg.
//
// Occupancy ledger (the point of this round): r10 = 4 blocks/CU x 4 waves =
// 4 waves/SIMD at 97us.  VALU 42% / LDS ~25% / HBM 26% / MFMA 4% -> latency-
// bound; throughput should scale with resident waves.  The ONLY clean way to
// add waves at 256-thread blocks: shrink LDS.  h2 staging (16x40 halves)
// OVERLAYS the h1 buffer (h1's ds_read_b128s complete before h2's writes
// issue -- ordered by the per-phase drains; r11 proved the overlay correct).
// LDS/block 32768 -> 27648 -> 5 blocks/CU (138KB), natural VGPR 84 <= 102 ->
// 5 waves/SIMD, 20 waves/CU.  NO launch-bounds pin beyond the proven (256,4)
// (forced pins are 0-for-3: r3/r8/r17 all spilled).  This is r11 minus its
// two poisons (the (256,5) pin and the frag-read stagger).
__global__ __launch_bounds__(256, 4) void mlp_mfma_kernel(
    const float* __restrict__ x,
    const float* __restrict__ alpha,
    const float* __restrict__ beta,
    const float* __restrict__ gamma,
    const float* __restrict__ gscal,
    const float* __restrict__ W1, const float* __restrict__ b1,
    const float* __restrict__ W2, const float* __restrict__ b2,
    const float* __restrict__ Wres, const float* __restrict__ bres,
    const float* __restrict__ W6, const float* __restrict__ b6,
    float* __restrict__ out, int B)
{
    const int lane = threadIdx.x & 63;
    const int wid  = threadIdx.x >> 6;
    const int c    = lane & 15;   // col (N) index / A-row index
    const int g    = lane >> 4;   // k-group 0..3

    // Weight-fragment table (block-shared): frags 0..11 = W1[t*3+s],
    // 12..15 = W2[12+t*2+s], 16..17 = Wres[16+t].  18 frags x 64 lanes x 16B.
    __shared__ __align__(16) _Float16 wtab[18 * 512];
    // per-wave activation staging; h2 (16x40, 640 halves) overlays the head
    // of h1 (16x72, 1152 halves).  LDS/block = 18432 + 4*2304 = 27648 B.
    __shared__ __align__(16) _Float16 h1buf[4][16 * 72];
    _Float16* h1b = h1buf[wid];          // NOT restrict: h1/h2 regions alias

    // ---- build weight tables once (wave 0) ----
    if (wid == 0) {
        float gm[8];
        #pragma unroll
        for (int j = 0; j < 8; ++j) {
            int k  = 8 * g + j;
            int kc = k < 3 ? 3 : (k > 22 ? 22 : k);     // clamp: safe load
            float gv = gamma[kc];
            gm[j] = (k >= 3 && k < 23) ? gv : 1.0f;
        }
        #pragma unroll
        for (int t = 0; t < 4; ++t)
            #pragma unroll
            for (int s = 0; s < 3; ++s)
                #pragma unroll
                for (int j = 0; j < 8; ++j) {
                    int k  = 32 * s + 8 * g + j;
                    int kc = k < 73 ? k : 72;           // clamp: no OOB load
                    float v = W1[(16 * t + c) * 73 + kc];
                    if (s == 0) v *= gm[j];             // gamma folded into s=0
                    wtab[(t * 3 + s) * 512 + lane * 8 + j] =
                        (k < 73) ? (_Float16)v : (_Float16)0.f;
                }
        #pragma unroll
        for (int t = 0; t < 2; ++t)
            #pragma unroll
            for (int s = 0; s < 2; ++s)
                #pragma unroll
                for (int j = 0; j < 8; ++j)
                    wtab[(12 + t * 2 + s) * 512 + lane * 8 + j] =
                        (_Float16)W2[(16 * t + c) * 64 + 32 * s + 8 * g + j];
        #pragma unroll
        for (int t = 0; t < 2; ++t)
            #pragma unroll
            for (int j = 0; j < 8; ++j)
                wtab[(16 + t) * 512 + lane * 8 + j] =
                    (_Float16)Wres[(16 * t + c) * 32 + 8 * g + j];
    }

    // biases / final weights stay in registers (10 regs)
    float b1f[4], b2f[2], brf[2], w6f[2];
    #pragma unroll
    for (int t = 0; t < 4; ++t) b1f[t] = b1[16 * t + c];
    #pragma unroll
    for (int t = 0; t < 2; ++t) { b2f[t] = b2[16 * t + c]; brf[t] = bres[16 * t + c]; w6f[t] = W6[16 * t + c]; }
    const float b6g = b6[0] + gscal[0];

    __syncthreads();   // table visible to all waves (once, outside hot loop)

    const _Float16* wt = wtab + lane * 8;   // shared vaddr; frag f at +f*512

    const int ntiles = B >> 4;
    const int totw   = gridDim.x * 4;
    for (int tile = blockIdx.x * 4 + wid; tile < ntiles; tile += totw) {
        const int R0 = tile << 4;
        const float* __restrict__ xr = x + (size_t)(R0 + c) * 73;

        // ---- x loads (issued up front) ----
        float xv0[8], xv1[8], xv2[8];
        #pragma unroll
        for (int j = 0; j < 8; ++j) xv0[j] = xr[8 * g + j];
        #pragma unroll
        for (int j = 0; j < 8; ++j) xv1[j] = xr[32 + 8 * g + j];
        #pragma unroll
        for (int j = 0; j < 8; ++j) {
            int k = 64 + 8 * g + j;
            float v = xr[k < 73 ? k : 72];
            xv2[j] = (k < 73) ? v : 0.f;
        }

        // embed gathers (only g==0 lanes own cols 0/1); consumed by the LAST
        // k-step's MFMAs
        float xa = 0.f, xb = 0.f;
        if (g == 0) {
            xa = alpha[(int)xv0[0]];
            xb = beta[(int)xv0[1]];
        }

        // ---- W1 frags from LDS (re-read each tile; drains block LICM) ----
        half8 w1f[4][3];
        #pragma unroll
        for (int t = 0; t < 4; ++t)
            #pragma unroll
            for (int s = 0; s < 3; ++s)
                w1f[t][s] = *reinterpret_cast<const half8*>(wt + (t * 3 + s) * 512);

        // ---- layer 1: 73->64.  k-steps 1,2 first (no gather dep) ----
        union H8 { half8 h8; fp16x2 h2[4]; };
        H8 a1u, a2u;
        #pragma unroll
        for (int j = 0; j < 4; ++j) {
            a1u.h2[j] = __builtin_amdgcn_cvt_pkrtz(xv1[2 * j], xv1[2 * j + 1]);
            a2u.h2[j] = __builtin_amdgcn_cvt_pkrtz(xv2[2 * j], xv2[2 * j + 1]);
        }
        f32x4 acc[4];
        #pragma unroll
        for (int t = 0; t < 4; ++t) { f32x4 z = { b1f[t], b1f[t], b1f[t], b1f[t] }; acc[t] = z; }
        #pragma unroll
        for (int t = 0; t < 4; ++t) acc[t] = MFMA16(a1u.h8, w1f[t][1], acc[t]);
        #pragma unroll
        for (int t = 0; t < 4; ++t) acc[t] = MFMA16(a2u.h8, w1f[t][2], acc[t]);

        // k-step 0 last: gamma pre-folded; cols 0/1 replaced by embeds
        H8 a0u;
        #pragma unroll
        for (int j = 0; j < 4; ++j)
            a0u.h2[j] = __builtin_amdgcn_cvt_pkrtz(xv0[2 * j], xv0[2 * j + 1]);
        {
            fp16x2 we = __builtin_amdgcn_cvt_pkrtz(xa, xb);
            if (g == 0) a0u.h2[0] = we;
        }
        #pragma unroll
        for (int t = 0; t < 4; ++t) acc[t] = MFMA16(a0u.h8, w1f[t][0], acc[t]);

        // GELU -> h1 to LDS (row = 4g+r, col = 16t+c, stride 72)
        #pragma unroll
        for (int t = 0; t < 4; ++t)
            #pragma unroll
            for (int r = 0; r < 4; ++r)
                h1b[(4 * g + r) * 72 + 16 * t + c] = (_Float16)gelu_f(acc[t][r]);

        asm volatile("s_waitcnt lgkmcnt(0)" ::: "memory");

        // ---- layer 2: 64->32 ----
        half8 w2f[2][2];
        #pragma unroll
        for (int t = 0; t < 2; ++t)
            #pragma unroll
            for (int s = 0; s < 2; ++s)
                w2f[t][s] = *reinterpret_cast<const half8*>(wt + (12 + t * 2 + s) * 512);

        half8 a2f0 = *reinterpret_cast<const half8*>(&h1b[c * 72 + 8 * g]);
        half8 a2f1 = *reinterpret_cast<const half8*>(&h1b[c * 72 + 32 + 8 * g]);
        f32x4 ac2[2];
        #pragma unroll
        for (int t = 0; t < 2; ++t) {
            f32x4 z = { b2f[t], b2f[t], b2f[t], b2f[t] };
            z = MFMA16(a2f0, w2f[t][0], z);
            ac2[t] = MFMA16(a2f1, w2f[t][1], z);
        }
        float h2c[2][4];
        #pragma unroll
        for (int t = 0; t < 2; ++t)
            #pragma unroll
            for (int r = 0; r < 4; ++r)
                h2c[t][r] = gelu_f(ac2[t][r]);

        // h2 to LDS -- OVERLAID on h1 (stride 40).  h1's b128 reads above are
        // complete (their results already fed MFMAs); per-wave DS in-order.
        #pragma unroll
        for (int t = 0; t < 2; ++t)
            #pragma unroll
            for (int r = 0; r < 4; ++r)
                h1b[(4 * g + r) * 40 + 16 * t + c] = (_Float16)h2c[t][r];

        asm volatile("s_waitcnt lgkmcnt(0)" ::: "memory");

        // ---- residual layer: C-init = bres + h2 (matching C-layout slots) ----
        half8 wrf[2];
        #pragma unroll
        for (int t = 0; t < 2; ++t)
            wrf[t] = *reinterpret_cast<const half8*>(wt + (16 + t) * 512);

        half8 arf = *reinterpret_cast<const half8*>(&h1b[c * 40 + 8 * g]);
        f32x4 acr[2];
        #pragma unroll
        for (int t = 0; t < 2; ++t) {
            f32x4 z = { brf[t] + h2c[t][0], brf[t] + h2c[t][1],
                        brf[t] + h2c[t][2], brf[t] + h2c[t][3] };
            acr[t] = MFMA16(arf, wrf[t], z);
        }

        // ---- final 32->1: per-lane partial, butterfly-reduce over c ----
        f32x4 p;
        #pragma unroll
        for (int r = 0; r < 4; ++r)
            p[r] = gelu_f(acr[0][r]) * w6f[0] + gelu_f(acr[1][r]) * w6f[1];
        #pragma unroll
        for (int m = 1; m < 16; m <<= 1) {
            #pragma unroll
            for (int r = 0; r < 4; ++r) p[r] += __shfl_xor(p[r], m, 64);
        }
        if (c == 0) {
            f32x4 o = { p[0] + b6g, p[1] + b6g, p[2] + b6g, p[3] + b6g };
            *reinterpret_cast<f32x4*>(out + R0 + 4 * g) = o;  // rows R0+4g..+3
        }
    }
}

extern "C" void kernel_launch(void* const* d_in, const int* in_sizes, int n_in,
                              void* d_out, int out_size, void* d_ws, size_t ws_size,
                              hipStream_t stream) {
    const float* x     = (const float*)d_in[0];
    const float* alpha = (const float*)d_in[1];
    const float* beta  = (const float*)d_in[2];
    const float* gamma = (const float*)d_in[3];
    const float* g     = (const float*)d_in[4];
    const float* W1    = (const float*)d_in[5];
    const float* b1    = (const float*)d_in[6];
    const float* W2    = (const float*)d_in[7];
    const float* b2    = (const float*)d_in[8];
    const float* Wres  = (const float*)d_in[9];
    const float* bres  = (const float*)d_in[10];
    const float* W6    = (const float*)d_in[11];
    const float* b6    = (const float*)d_in[12];
    float* out = (float*)d_out;

    int B = out_size;          // 1e6 rows; divisible by 16
    // 1280 blocks = 5 blocks/CU (LDS 27648 x 5 = 138KB; VGPR 84 <= 102) ->
    // 20 waves/CU = 5 waves/SIMD.  The clean occupancy experiment.
    int nblocks = 1280;
    mlp_mfma_kernel<<<nblocks, 256, 0, stream>>>(x, alpha, beta, gamma, g,
                                                 W1, b1, W2, b2, Wres, bres,
                                                 W6, b6, out, B);
}